// Round 12
// baseline (104.562 us; speedup 1.0000x reference)
//
#include <hip/hip_runtime.h>
#include <math.h>

#define N_INW     1024
#define N_DEPTH   8
#define N_GROW    512
#define N_BATCH   4096
#define N_THREADS 64     // ONE wave per WG; wave owns cols {2b', 2b'+1}
#define N_LAYERS  64

typedef __attribute__((ext_vector_type(2))) float F2;
typedef decltype(__builtin_amdgcn_cvt_pkrtz(0.f, 0.f)) H2;   // half2

// ---- setup: cs planes + precomputed LDS byte-offsets for all gathers ----
// layer g: cos plane [g*1024 + p], sin plane [g*1024 + 512 + p].
__global__ void precompute_kernel(const float* __restrict__ angles,
                                  const int*   __restrict__ indices,
                                  float* __restrict__ cs,
                                  int*   __restrict__ addrs) {
    int i = blockIdx.x * blockDim.x + threadIdx.x;
    if (i < N_LAYERS * 512) {
        int g = i >> 9, p = i & 511;
        float a = angles[i];
        cs[g * 1024 + p]       = cosf(a);
        cs[g * 1024 + 512 + p] = sinf(a);
    }
    if (i < N_DEPTH * N_INW) {
        int v = indices[i];
        addrs[i] = (v + (v >> 4)) << 2;
    }
}

// fp16 slab: row r -> half2 at byte (r + (r>>4))<<2; 19584 B -> 8 WGs/CU.
#define ADDR(r) ((((r) + ((r) >> 4))) << 2)

#define LD2(A) ({ H2 _h = *(const H2*)(L + (A));                               \
                  F2 _v; _v.x = (float)_h.x; _v.y = (float)_h.y; _v; })
#define ST2(A, V) do { F2 _w = (V);                                            \
    *(H2*)(L + (A)) = __builtin_amdgcn_cvt_pkrtz(_w.x, _w.y); } while (0)

// cos/sin for layer K of the CURRENT module (runtime bases csb / anb)
#define LDCS_K(K, CA, CB, SA, SB) do { if (USE_TABLE) {                        \
    const float4* _c = (const float4*)(csb + (K)*1024 + (blk<<3));             \
    const float4* _s = (const float4*)(csb + (K)*1024 + 512 + (blk<<3));       \
    CA = _c[0]; CB = _c[1]; SA = _s[0]; SB = _s[1];                            \
  } else {                                                                     \
    const float4* _p = (const float4*)(anb + (K)*512 + (blk<<3));              \
    float4 _a = _p[0], _b = _p[1];                                             \
    __sincosf(_a.x, &SA.x, &CA.x); __sincosf(_a.y, &SA.y, &CA.y);              \
    __sincosf(_a.z, &SA.z, &CA.z); __sincosf(_a.w, &SA.w, &CA.w);              \
    __sincosf(_b.x, &SB.x, &CB.x); __sincosf(_b.y, &SB.y, &CB.y);              \
    __sincosf(_b.z, &SB.z, &CB.z); __sincosf(_b.w, &SB.w, &CB.w);              \
  } } while (0)

#define TR(v) (((v) + ((v) >> 4)) << 2)
// gather byte-offsets from runtime bases (PA = addr_tab slice, PI = indices slice)
#define LDADDR_P(PA, PI) do { if (USE_TABLE) {                                 \
    const int4* _ip = (const int4*)((PA) + (blk<<4));                          \
    i0 = _ip[0]; i1 = _ip[1]; i2 = _ip[2]; i3 = _ip[3];                        \
  } else {                                                                     \
    const int4* _ip = (const int4*)((PI) + (blk<<4));                          \
    int4 _v0=_ip[0], _v1=_ip[1], _v2=_ip[2], _v3=_ip[3];                       \
    i0.x=TR(_v0.x); i0.y=TR(_v0.y); i0.z=TR(_v0.z); i0.w=TR(_v0.w);            \
    i1.x=TR(_v1.x); i1.y=TR(_v1.y); i1.z=TR(_v1.z); i1.w=TR(_v1.w);            \
    i2.x=TR(_v2.x); i2.y=TR(_v2.y); i2.z=TR(_v2.z); i2.w=TR(_v2.w);            \
    i3.x=TR(_v3.x); i3.y=TR(_v3.y); i3.z=TR(_v3.z); i3.w=TR(_v3.w);            \
  } } while (0)

#define ROTP(LO, HI, CC, SS) do { F2 _l = LO, _h = HI;                         \
    LO = CC * _l + SS * _h; HI = CC * _h - SS * _l; } while (0)

#define ROTS1(CA,CB,SA,SB) do {                                                \
    ROTP(x0,x1,CA.x,SA.x);  ROTP(x2,x3,CA.y,SA.y);                             \
    ROTP(x4,x5,CA.z,SA.z);  ROTP(x6,x7,CA.w,SA.w);                             \
    ROTP(x8,x9,CB.x,SB.x);  ROTP(x10,x11,CB.y,SB.y);                           \
    ROTP(x12,x13,CB.z,SB.z);ROTP(x14,x15,CB.w,SB.w); } while (0)
#define ROTS2(CA,CB,SA,SB) do {                                                \
    ROTP(x0,x2,CA.x,SA.x);  ROTP(x1,x3,CA.y,SA.y);                             \
    ROTP(x4,x6,CA.z,SA.z);  ROTP(x5,x7,CA.w,SA.w);                             \
    ROTP(x8,x10,CB.x,SB.x); ROTP(x9,x11,CB.y,SB.y);                            \
    ROTP(x12,x14,CB.z,SB.z);ROTP(x13,x15,CB.w,SB.w); } while (0)
#define ROTS4(CA,CB,SA,SB) do {                                                \
    ROTP(x0,x4,CA.x,SA.x);  ROTP(x1,x5,CA.y,SA.y);                             \
    ROTP(x2,x6,CA.z,SA.z);  ROTP(x3,x7,CA.w,SA.w);                             \
    ROTP(x8,x12,CB.x,SB.x); ROTP(x9,x13,CB.y,SB.y);                            \
    ROTP(x10,x14,CB.z,SB.z);ROTP(x11,x15,CB.w,SB.w); } while (0)
#define ROTS8(CA,CB,SA,SB) do {                                                \
    ROTP(x0,x8,CA.x,SA.x);  ROTP(x1,x9,CA.y,SA.y);                             \
    ROTP(x2,x10,CA.z,SA.z); ROTP(x3,x11,CA.w,SA.w);                            \
    ROTP(x4,x12,CB.x,SB.x); ROTP(x5,x13,CB.y,SB.y);                            \
    ROTP(x6,x14,CB.z,SB.z); ROTP(x7,x15,CB.w,SB.w); } while (0)

#define ACT1(X, BB) do { F2 _p = (X) + (BB);                                   \
    F2 _t = _p * _p + 1.0f;                                                    \
    F2 _r; _r.x = __builtin_amdgcn_sqrtf(_t.x);                                \
    _r.y = __builtin_amdgcn_sqrtf(_t.y);                                       \
    X = 0.5f * (_p + _r); } while (0)

#define FENCE() __builtin_amdgcn_sched_barrier(0)

// gather: declares a0..a15 (byte addrs) and x0..x15 (values)
#define GATHER()                                                               \
  const int a0=i0.x, a1=i0.y, a2=i0.z, a3=i0.w, a4=i1.x, a5=i1.y,              \
            a6=i1.z, a7=i1.w, a8=i2.x, a9=i2.y, a10=i2.z, a11=i2.w,            \
            a12=i3.x, a13=i3.y, a14=i3.z, a15=i3.w;                            \
  F2 x0=LD2(a0), x1=LD2(a1), x2=LD2(a2), x3=LD2(a3),                           \
     x4=LD2(a4), x5=LD2(a5), x6=LD2(a6), x7=LD2(a7),                           \
     x8=LD2(a8), x9=LD2(a9), x10=LD2(a10), x11=LD2(a11),                       \
     x12=LD2(a12), x13=LD2(a13), x14=LD2(a14), x15=LD2(a15);

// ROLLED module loop: body ~4-5 KB of code, I$-resident and reused 8x.
// (r3-r11 were fully-unrolled ~30 KB straight-line bodies: zero I$ reuse,
// ~480 cold lines x ~150 cyc L2 fetch ~= the entire 108K-cycle wall.)
template <bool USE_TABLE>
__global__ __launch_bounds__(N_THREADS, 2)   // 2 waves/EU = 8 WGs/CU (LDS cap)
void butterfly_fused_kernel(const float* __restrict__ input,
                            const float* __restrict__ scales,
                            const float* __restrict__ biases,
                            const int*   __restrict__ indices,
                            const float* __restrict__ cs_tab,
                            const int*   __restrict__ addr_tab,
                            const float* __restrict__ angles,
                            float* __restrict__ out) {
    extern __shared__ float ldsbuf[];
    char* L = (char*)ldsbuf;
    const int blk = threadIdx.x;     // butterfly block = lane (single-wave WG)
    // XCD swizzle: blockIdx%8 == x owns columns [x*512,(x+1)*512).
    const int b   = blockIdx.x;
    const int cg  = (((b & 7) * 256) + (b >> 3)) * 2;

    // cross-module prefetch state (IN-cs, bias, gather addrs of CURRENT module)
    float4 ca0,cb0,sa0,sb0, ca1,cb1,sa1,sb1, ca2,cb2,sa2,sb2, ca3,cb3,sa3,sb3;
    float4 bA, bB;
    int4 i0, i1, i2, i3;

    // runtime per-module bases
    const float* csb = cs_tab;                 // +8192 per module
    const float* anb = angles;                 // +4096 per module
    const int*   atb = addr_tab + N_INW;       // module m+1 gather addrs
    const int*   inb = indices + N_INW;
    const float* bnb = biases + N_GROW;        // module m+1 bias

    // prologue: module 0 params
    LDADDR_P(addr_tab, indices);
    LDCS_K(0, ca0,cb0,sa0,sb0);
    LDCS_K(1, ca1,cb1,sa1,sb1);
    LDCS_K(2, ca2,cb2,sa2,sb2);
    LDCS_K(3, ca3,cb3,sa3,sb3);
    { const float4* bp = (const float4*)(biases + (blk << 3));
      bA = bp[0]; bB = bp[1]; }

    // init: rows 0..1023 = scales[r] * input[r][cg..cg+1]
#pragma unroll
    for (int k = 0; k < 16; ++k) {
        const int r = (k << 6) + blk;
        F2 v = *(const F2*)(input + (size_t)r * N_BATCH + cg);
        ST2(ADDR(r), scales[r] * v);
    }

#pragma unroll 1
    for (int m = 0; m < 7; ++m) {
        // ---- load block A: gather + this module's OUT-phase cs ----
        GATHER();
        float4 da0,db0,ta0,tb0, da1,db1,ta1,tb1, da2,db2,ta2,tb2, da3,db3,ta3,tb3;
        LDCS_K(4, da0,db0,ta0,tb0);
        LDCS_K(5, da1,db1,ta1,tb1);
        LDCS_K(6, da2,db2,ta2,tb2);
        LDCS_K(7, da3,db3,ta3,tb3);
        FENCE();
        // ---- consume IN-cs (prefetched one module ago) ----
        ROTS1(ca0,cb0,sa0,sb0);
        ROTS2(ca1,cb1,sa1,sb1);
        ROTS4(ca2,cb2,sa2,sb2);
        ROTS8(ca3,cb3,sa3,sb3);
        ACT1(x0,bA.x); ACT1(x1,bA.y); ACT1(x2,bA.z); ACT1(x3,bA.w);
        ACT1(x4,bB.x); ACT1(x5,bB.y); ACT1(x6,bB.z); ACT1(x7,bB.w);
        // append act rows
        const int br = N_INW + m * N_GROW + (blk << 3);
        const int ab = ADDR(br);
        ST2(ab+ 0,x0); ST2(ab+ 4,x1); ST2(ab+ 8,x2); ST2(ab+12,x3);
        ST2(ab+16,x4); ST2(ab+20,x5); ST2(ab+24,x6); ST2(ab+28,x7);
        // ---- load block B: next module's IN-cs + gather addrs + bias ----
        LDCS_K(8,  ca0,cb0,sa0,sb0);
        LDCS_K(9,  ca1,cb1,sa1,sb1);
        LDCS_K(10, ca2,cb2,sa2,sb2);
        LDCS_K(11, ca3,cb3,sa3,sb3);
        LDADDR_P(atb, inb);
        { const float4* bp = (const float4*)(bnb + (blk << 3));
          bA = bp[0]; bB = bp[1]; }
        FENCE();
        // ---- consume OUT-cs (prefetched in block A) ----
        ROTS1(da0,db0,ta0,tb0);
        ROTS2(da1,db1,ta1,tb1);
        ROTS4(da2,db2,ta2,tb2);
        ROTS8(da3,db3,ta3,tb3);
        ST2(a0,x0);  ST2(a1,x1);  ST2(a2,x2);  ST2(a3,x3);
        ST2(a4,x4);  ST2(a5,x5);  ST2(a6,x6);  ST2(a7,x7);
        ST2(a8,x8);  ST2(a9,x9);  ST2(a10,x10); ST2(a11,x11);
        ST2(a12,x12); ST2(a13,x13); ST2(a14,x14); ST2(a15,x15);
        csb += 8192; anb += 4096; atb += N_INW; inb += N_INW; bnb += N_GROW;
    }

    // epilogue: module 7 — OUT rotations + scatter are dead code; output =
    // module-7 activations.
    {
        GATHER();
        FENCE();
        ROTS1(ca0,cb0,sa0,sb0);
        ROTS2(ca1,cb1,sa1,sb1);
        ROTS4(ca2,cb2,sa2,sb2);
        ROTS8(ca3,cb3,sa3,sb3);
        ACT1(x0,bA.x); ACT1(x1,bA.y); ACT1(x2,bA.z); ACT1(x3,bA.w);
        ACT1(x4,bB.x); ACT1(x5,bB.y); ACT1(x6,bB.z); ACT1(x7,bB.w);
        *(F2*)(out + (size_t)((blk<<3)+0)*N_BATCH + cg) = x0;
        *(F2*)(out + (size_t)((blk<<3)+1)*N_BATCH + cg) = x1;
        *(F2*)(out + (size_t)((blk<<3)+2)*N_BATCH + cg) = x2;
        *(F2*)(out + (size_t)((blk<<3)+3)*N_BATCH + cg) = x3;
        *(F2*)(out + (size_t)((blk<<3)+4)*N_BATCH + cg) = x4;
        *(F2*)(out + (size_t)((blk<<3)+5)*N_BATCH + cg) = x5;
        *(F2*)(out + (size_t)((blk<<3)+6)*N_BATCH + cg) = x6;
        *(F2*)(out + (size_t)((blk<<3)+7)*N_BATCH + cg) = x7;
    }
}

// ---------------- host ----------------
extern "C" void kernel_launch(void* const* d_in, const int* in_sizes, int n_in,
                              void* d_out, int out_size, void* d_ws, size_t ws_size,
                              hipStream_t stream) {
    const float* input   = (const float*)d_in[0];
    const float* scales  = (const float*)d_in[1];
    const float* angles  = (const float*)d_in[2];
    const float* biases  = (const float*)d_in[3];
    const int*   indices = (const int*)d_in[4];
    float* out = (float*)d_out;

    const size_t cs_bytes  = (size_t)N_LAYERS * 2 * 512 * sizeof(float);   // 256 KB
    const size_t adr_bytes = (size_t)N_DEPTH * N_INW * sizeof(int);        // 32 KB
    // fp16 slab: 4608*4 + 288*4 = 19584 B per WG -> 8 WGs/CU
    const size_t lds_bytes = (size_t)4608 * 4 + 288 * 4;
    const int grid = N_BATCH / 2;                                          // 2048 WGs

    if (ws_size >= cs_bytes + adr_bytes) {
        float* cs  = (float*)d_ws;
        int* addrs = (int*)((char*)d_ws + cs_bytes);
        precompute_kernel<<<N_LAYERS * 512 / 256, 256, 0, stream>>>(angles, indices, cs, addrs);
        butterfly_fused_kernel<true><<<grid, N_THREADS, lds_bytes, stream>>>(
            input, scales, biases, indices, cs, addrs, angles, out);
    } else {
        butterfly_fused_kernel<false><<<grid, N_THREADS, lds_bytes, stream>>>(
            input, scales, biases, indices, nullptr, nullptr, angles, out);
    }
}

// Round 13
// 100.526 us; speedup vs baseline: 1.0402x; 1.0402x over previous
//
#include <hip/hip_runtime.h>
#include <math.h>

#define N_INW     1024
#define N_DEPTH   8
#define N_GROW    512
#define N_BATCH   4096
#define N_THREADS 64     // ONE wave per WG; wave owns cols {2b', 2b'+1}
#define N_LAYERS  64

typedef __attribute__((ext_vector_type(2))) float F2;
typedef decltype(__builtin_amdgcn_cvt_pkrtz(0.f, 0.f)) H2;   // packed half2

// ---- setup: fp16 cs table + precomputed LDS byte-offsets ----
// layer g, lane blk: 8 cos halves at byte g*2048 + blk*32, 8 sin halves at +16.
__global__ void precompute_kernel(const float* __restrict__ angles,
                                  const int*   __restrict__ indices,
                                  _Float16* __restrict__ csh,
                                  int*   __restrict__ addrs) {
    int i = blockIdx.x * blockDim.x + threadIdx.x;
    if (i < N_LAYERS * 512) {
        int g = i >> 9, p = i & 511, blk = p >> 3, j = p & 7;
        float a = angles[i];
        _Float16* base = csh + g * 1024 + blk * 16;   // halves
        base[j]     = (_Float16)cosf(a);
        base[8 + j] = (_Float16)sinf(a);
    }
    if (i < N_DEPTH * N_INW) {
        int v = indices[i];
        addrs[i] = (v + (v >> 4)) << 2;
    }
}

// fp16 slab: row r -> half2 at byte (r + (r>>4))<<2; 19584 B -> 8 WGs/CU.
#define ADDR(r) ((((r) + ((r) >> 4))) << 2)

#define LD2(A) ({ H2 _h = *(const H2*)(L + (A));                               \
                  F2 _v; _v.x = (float)_h.x; _v.y = (float)_h.y; _v; })
#define ST2(A, V) do { F2 _w = (V);                                            \
    *(H2*)(L + (A)) = __builtin_amdgcn_cvt_pkrtz(_w.x, _w.y); } while (0)

#define PKU(x, y) __builtin_bit_cast(unsigned int,                             \
                      __builtin_amdgcn_cvt_pkrtz((x), (y)))

// unpack 8 packed halves (uint4) -> two float4
#define UNPK(Q, FA, FB) do {                                                   \
    H2 _h0 = __builtin_bit_cast(H2, (Q).x), _h1 = __builtin_bit_cast(H2, (Q).y),\
       _h2 = __builtin_bit_cast(H2, (Q).z), _h3 = __builtin_bit_cast(H2, (Q).w);\
    FA.x = (float)_h0.x; FA.y = (float)_h0.y; FA.z = (float)_h1.x;             \
    FA.w = (float)_h1.y; FB.x = (float)_h2.x; FB.y = (float)_h2.y;             \
    FB.z = (float)_h3.x; FB.w = (float)_h3.y; } while (0)

// ---- per-set register state (A / B ping-pong, full-module prefetch) ----
#define DECL_SET(P)                                                            \
    uint4 P##c0, P##s0, P##c1, P##s1, P##c2, P##s2, P##c3, P##s3,              \
          P##c4, P##s4, P##c5, P##s5, P##c6, P##s6, P##c7, P##s7;              \
    int4  P##i0, P##i1, P##i2, P##i3;                                          \
    float4 P##bA, P##bB;

// synthesize one packed layer from angles (fallback path)
#define SYN1(P, K, ANB) do {                                                   \
    const float4* _p = (const float4*)((ANB) + (K)*512 + (blk << 3));          \
    float4 _u = _p[0], _v = _p[1];                                             \
    float _c0,_c1,_c2,_c3,_c4,_c5,_c6,_c7,_t0,_t1,_t2,_t3,_t4,_t5,_t6,_t7;     \
    __sincosf(_u.x,&_t0,&_c0); __sincosf(_u.y,&_t1,&_c1);                      \
    __sincosf(_u.z,&_t2,&_c2); __sincosf(_u.w,&_t3,&_c3);                      \
    __sincosf(_v.x,&_t4,&_c4); __sincosf(_v.y,&_t5,&_c5);                      \
    __sincosf(_v.z,&_t6,&_c6); __sincosf(_v.w,&_t7,&_c7);                      \
    P##c##K = make_uint4(PKU(_c0,_c1),PKU(_c2,_c3),PKU(_c4,_c5),PKU(_c6,_c7)); \
    P##s##K = make_uint4(PKU(_t0,_t1),PKU(_t2,_t3),PKU(_t4,_t5),PKU(_t6,_t7)); \
  } while (0)

// load (or synthesize) a module's cs set; CSN = byte base, ANB = angle base
#define LOADCS1(P, K, CSN, ANB) do { if (USE_TABLE) {                          \
    const char* _b = (CSN) + (blk << 5) + (K)*2048;                            \
    P##c##K = *(const uint4*)(_b); P##s##K = *(const uint4*)(_b + 16);         \
  } else { SYN1(P, K, ANB); } } while (0)

#define LOADCS8(P, CSN, ANB) do {                                              \
    LOADCS1(P,0,CSN,ANB); LOADCS1(P,1,CSN,ANB); LOADCS1(P,2,CSN,ANB);          \
    LOADCS1(P,3,CSN,ANB); LOADCS1(P,4,CSN,ANB); LOADCS1(P,5,CSN,ANB);          \
    LOADCS1(P,6,CSN,ANB); LOADCS1(P,7,CSN,ANB); } while (0)
#define LOADCS4(P, CSN, ANB) do {                                              \
    LOADCS1(P,0,CSN,ANB); LOADCS1(P,1,CSN,ANB); LOADCS1(P,2,CSN,ANB);          \
    LOADCS1(P,3,CSN,ANB); } while (0)

#define TR(v) (((v) + ((v) >> 4)) << 2)
#define LOAD_AB(P, ATN, INB, BIN) do { if (USE_TABLE) {                        \
    const int4* _ip = (const int4*)((ATN) + (blk << 4));                       \
    P##i0=_ip[0]; P##i1=_ip[1]; P##i2=_ip[2]; P##i3=_ip[3];                    \
  } else {                                                                     \
    const int4* _ip = (const int4*)((INB) + (blk << 4));                       \
    int4 _v0=_ip[0], _v1=_ip[1], _v2=_ip[2], _v3=_ip[3];                       \
    P##i0.x=TR(_v0.x); P##i0.y=TR(_v0.y); P##i0.z=TR(_v0.z); P##i0.w=TR(_v0.w);\
    P##i1.x=TR(_v1.x); P##i1.y=TR(_v1.y); P##i1.z=TR(_v1.z); P##i1.w=TR(_v1.w);\
    P##i2.x=TR(_v2.x); P##i2.y=TR(_v2.y); P##i2.z=TR(_v2.z); P##i2.w=TR(_v2.w);\
    P##i3.x=TR(_v3.x); P##i3.y=TR(_v3.y); P##i3.z=TR(_v3.z); P##i3.w=TR(_v3.w);\
  }                                                                            \
  const float4* _bp = (const float4*)((BIN) + (blk << 3));                     \
  P##bA = _bp[0]; P##bB = _bp[1]; } while (0)

#define ROTP(LO, HI, CC, SS) do { F2 _l = LO, _h = HI;                         \
    LO = CC * _l + SS * _h; HI = CC * _h - SS * _l; } while (0)

#define ROTS1(CA,CB,SA,SB) do {                                                \
    ROTP(x0,x1,CA.x,SA.x);  ROTP(x2,x3,CA.y,SA.y);                             \
    ROTP(x4,x5,CA.z,SA.z);  ROTP(x6,x7,CA.w,SA.w);                             \
    ROTP(x8,x9,CB.x,SB.x);  ROTP(x10,x11,CB.y,SB.y);                           \
    ROTP(x12,x13,CB.z,SB.z);ROTP(x14,x15,CB.w,SB.w); } while (0)
#define ROTS2(CA,CB,SA,SB) do {                                                \
    ROTP(x0,x2,CA.x,SA.x);  ROTP(x1,x3,CA.y,SA.y);                             \
    ROTP(x4,x6,CA.z,SA.z);  ROTP(x5,x7,CA.w,SA.w);                             \
    ROTP(x8,x10,CB.x,SB.x); ROTP(x9,x11,CB.y,SB.y);                            \
    ROTP(x12,x14,CB.z,SB.z);ROTP(x13,x15,CB.w,SB.w); } while (0)
#define ROTS4(CA,CB,SA,SB) do {                                                \
    ROTP(x0,x4,CA.x,SA.x);  ROTP(x1,x5,CA.y,SA.y);                             \
    ROTP(x2,x6,CA.z,SA.z);  ROTP(x3,x7,CA.w,SA.w);                             \
    ROTP(x8,x12,CB.x,SB.x); ROTP(x9,x13,CB.y,SB.y);                            \
    ROTP(x10,x14,CB.z,SB.z);ROTP(x11,x15,CB.w,SB.w); } while (0)
#define ROTS8(CA,CB,SA,SB) do {                                                \
    ROTP(x0,x8,CA.x,SA.x);  ROTP(x1,x9,CA.y,SA.y);                             \
    ROTP(x2,x10,CA.z,SA.z); ROTP(x3,x11,CA.w,SA.w);                            \
    ROTP(x4,x12,CB.x,SB.x); ROTP(x5,x13,CB.y,SB.y);                            \
    ROTP(x6,x14,CB.z,SB.z); ROTP(x7,x15,CB.w,SB.w); } while (0)

// consume one packed cs layer
#define ROTL(P, K, ROTM) do { float4 _CA,_CB,_SA,_SB;                          \
    UNPK(P##c##K, _CA, _CB); UNPK(P##s##K, _SA, _SB);                          \
    ROTM(_CA,_CB,_SA,_SB); } while (0)

#define ACT1(X, BB) do { F2 _p = (X) + (BB);                                   \
    F2 _t = _p * _p + 1.0f;                                                    \
    F2 _r; _r.x = __builtin_amdgcn_sqrtf(_t.x);                                \
    _r.y = __builtin_amdgcn_sqrtf(_t.y);                                       \
    X = 0.5f * (_p + _r); } while (0)

#define FENCE() __builtin_amdgcn_sched_barrier(0)

// process module M with set P; prefetch next module into set N.
// FULL=1 loads all 8 next layers, FULL=0 only the IN 4 (module 7).
#define PROC_MOD(P, N, CSN, ANN, ATN, INB, BIN, M, FULL) do {                  \
  const int a0=P##i0.x, a1=P##i0.y, a2=P##i0.z, a3=P##i0.w,                    \
            a4=P##i1.x, a5=P##i1.y, a6=P##i1.z, a7=P##i1.w,                    \
            a8=P##i2.x, a9=P##i2.y, a10=P##i2.z, a11=P##i2.w,                  \
            a12=P##i3.x, a13=P##i3.y, a14=P##i3.z, a15=P##i3.w;                \
  F2 x0=LD2(a0), x1=LD2(a1), x2=LD2(a2), x3=LD2(a3),                           \
     x4=LD2(a4), x5=LD2(a5), x6=LD2(a6), x7=LD2(a7),                           \
     x8=LD2(a8), x9=LD2(a9), x10=LD2(a10), x11=LD2(a11),                       \
     x12=LD2(a12), x13=LD2(a13), x14=LD2(a14), x15=LD2(a15);                   \
  if (FULL) { LOADCS8(N, CSN, ANN); } else { LOADCS4(N, CSN, ANN); }           \
  FENCE();                                                                     \
  /* consume module M's params — loaded a FULL module ago */                   \
  ROTL(P,0,ROTS1); ROTL(P,1,ROTS2); ROTL(P,2,ROTS4); ROTL(P,3,ROTS8);          \
  ACT1(x0,P##bA.x); ACT1(x1,P##bA.y); ACT1(x2,P##bA.z); ACT1(x3,P##bA.w);      \
  ACT1(x4,P##bB.x); ACT1(x5,P##bB.y); ACT1(x6,P##bB.z); ACT1(x7,P##bB.w);      \
  const int _ab = ADDR(N_INW + (M)*N_GROW + (blk << 3));                       \
  ST2(_ab+ 0,x0); ST2(_ab+ 4,x1); ST2(_ab+ 8,x2); ST2(_ab+12,x3);              \
  ST2(_ab+16,x4); ST2(_ab+20,x5); ST2(_ab+24,x6); ST2(_ab+28,x7);              \
  LOAD_AB(N, ATN, INB, BIN);                                                   \
  FENCE();                                                                     \
  ROTL(P,4,ROTS1); ROTL(P,5,ROTS2); ROTL(P,6,ROTS4); ROTL(P,7,ROTS8);          \
  ST2(a0,x0);  ST2(a1,x1);  ST2(a2,x2);  ST2(a3,x3);                           \
  ST2(a4,x4);  ST2(a5,x5);  ST2(a6,x6);  ST2(a7,x7);                           \
  ST2(a8,x8);  ST2(a9,x9);  ST2(a10,x10); ST2(a11,x11);                        \
  ST2(a12,x12); ST2(a13,x13); ST2(a14,x14); ST2(a15,x15);                      \
} while (0)

template <bool USE_TABLE>
__global__ __launch_bounds__(N_THREADS, 2)   // keep allocator <=256 VGPR
void butterfly_fused_kernel(const float* __restrict__ input,
                            const float* __restrict__ scales,
                            const float* __restrict__ biases,
                            const int*   __restrict__ indices,
                            const char*  __restrict__ cs_tab,
                            const int*   __restrict__ addr_tab,
                            const float* __restrict__ angles,
                            float* __restrict__ out) {
    extern __shared__ float ldsbuf[];
    char* L = (char*)ldsbuf;
    const int blk = threadIdx.x;     // butterfly block = lane (single-wave WG)
    const int b   = blockIdx.x;
    const int cg  = (((b & 7) * 256) + (b >> 3)) * 2;   // XCD swizzle

    DECL_SET(A) DECL_SET(B)

    // prologue: module 0 params into A
    LOADCS8(A, cs_tab, angles);
    LOAD_AB(A, addr_tab, indices, biases);

    // init: rows 0..1023 = scales[r] * input[r][cg..cg+1]
#pragma unroll
    for (int k = 0; k < 16; ++k) {
        const int r = (k << 6) + blk;
        F2 v = *(const F2*)(input + (size_t)r * N_BATCH + cg);
        ST2(ADDR(r), scales[r] * v);
    }

    // next-module bases (module 1)
    const char*  csn = cs_tab + 16384;
    const float* ann = angles + 4096;
    const int*   atn = addr_tab + N_INW;
    const int*   inb = indices + N_INW;
    const float* bin = biases + N_GROW;

#pragma unroll 1
    for (int t = 0; t < 3; ++t) {
        const int m = 2 * t;
        PROC_MOD(A, B, csn, ann, atn, inb, bin, m, 1);
        csn += 16384; ann += 4096; atn += N_INW; inb += N_INW; bin += N_GROW;
        PROC_MOD(B, A, csn, ann, atn, inb, bin, m + 1, 1);
        csn += 16384; ann += 4096; atn += N_INW; inb += N_INW; bin += N_GROW;
    }
    // module 6 (A), prefetching module 7's IN layers into B
    PROC_MOD(A, B, csn, ann, atn, inb, bin, 6, 0);

    // epilogue: module 7 (B) — OUT rotations + scatter are dead code;
    // output = module-7 activations.
    {
        const int a0=Bi0.x, a1=Bi0.y, a2=Bi0.z, a3=Bi0.w,
                  a4=Bi1.x, a5=Bi1.y, a6=Bi1.z, a7=Bi1.w;
        F2 x0=LD2(a0), x1=LD2(a1), x2=LD2(a2), x3=LD2(a3),
           x4=LD2(a4), x5=LD2(a5), x6=LD2(a6), x7=LD2(a7);
        F2 x8=LD2(Bi2.x), x9=LD2(Bi2.y), x10=LD2(Bi2.z), x11=LD2(Bi2.w),
           x12=LD2(Bi3.x), x13=LD2(Bi3.y), x14=LD2(Bi3.z), x15=LD2(Bi3.w);
        FENCE();
        ROTL(B,0,ROTS1); ROTL(B,1,ROTS2); ROTL(B,2,ROTS4); ROTL(B,3,ROTS8);
        ACT1(x0,BbA.x); ACT1(x1,BbA.y); ACT1(x2,BbA.z); ACT1(x3,BbA.w);
        ACT1(x4,BbB.x); ACT1(x5,BbB.y); ACT1(x6,BbB.z); ACT1(x7,BbB.w);
        *(F2*)(out + (size_t)((blk<<3)+0)*N_BATCH + cg) = x0;
        *(F2*)(out + (size_t)((blk<<3)+1)*N_BATCH + cg) = x1;
        *(F2*)(out + (size_t)((blk<<3)+2)*N_BATCH + cg) = x2;
        *(F2*)(out + (size_t)((blk<<3)+3)*N_BATCH + cg) = x3;
        *(F2*)(out + (size_t)((blk<<3)+4)*N_BATCH + cg) = x4;
        *(F2*)(out + (size_t)((blk<<3)+5)*N_BATCH + cg) = x5;
        *(F2*)(out + (size_t)((blk<<3)+6)*N_BATCH + cg) = x6;
        *(F2*)(out + (size_t)((blk<<3)+7)*N_BATCH + cg) = x7;
    }
}

// ---------------- host ----------------
extern "C" void kernel_launch(void* const* d_in, const int* in_sizes, int n_in,
                              void* d_out, int out_size, void* d_ws, size_t ws_size,
                              hipStream_t stream) {
    const float* input   = (const float*)d_in[0];
    const float* scales  = (const float*)d_in[1];
    const float* angles  = (const float*)d_in[2];
    const float* biases  = (const float*)d_in[3];
    const int*   indices = (const int*)d_in[4];
    float* out = (float*)d_out;

    const size_t cs_bytes  = (size_t)N_LAYERS * 2048;                    // 128 KB fp16
    const size_t adr_bytes = (size_t)N_DEPTH * N_INW * sizeof(int);      // 32 KB
    const size_t lds_bytes = (size_t)4608 * 4 + 288 * 4;                 // 19584 B
    const int grid = N_BATCH / 2;                                        // 2048 WGs

    if (ws_size >= cs_bytes + adr_bytes) {
        _Float16* csh = (_Float16*)d_ws;
        int* addrs = (int*)((char*)d_ws + cs_bytes);
        precompute_kernel<<<(N_LAYERS * 512 + 255) / 256, 256, 0, stream>>>(
            angles, indices, csh, addrs);
        butterfly_fused_kernel<true><<<grid, N_THREADS, lds_bytes, stream>>>(
            input, scales, biases, indices, (const char*)csh, addrs, angles, out);
    } else {
        butterfly_fused_kernel<false><<<grid, N_THREADS, lds_bytes, stream>>>(
            input, scales, biases, indices, nullptr, nullptr, angles, out);
    }
}

// Round 14
// 98.326 us; speedup vs baseline: 1.0634x; 1.0224x over previous
//
#include <hip/hip_runtime.h>
#include <math.h>

#define N_INW     1024
#define N_DEPTH   8
#define N_GROW    512
#define N_BATCH   4096
#define N_THREADS 128    // 2 independent waves/WG; wave cp owns its own slab
#define N_LAYERS  64
#define SLAB_B    19584  // (4608 + 288 pad) * 4 B per wave

typedef __attribute__((ext_vector_type(2))) float    F2;
typedef __attribute__((ext_vector_type(2))) _Float16 h2;

// ---- setup: fp16 cs table + precomputed LDS byte-offsets ----
// layer g, lane blk: 8 cos halves at byte g*2048 + blk*32, 8 sin halves at +16.
__global__ void precompute_kernel(const float* __restrict__ angles,
                                  const int*   __restrict__ indices,
                                  _Float16* __restrict__ csh,
                                  int*   __restrict__ addrs) {
    int i = blockIdx.x * blockDim.x + threadIdx.x;
    if (i < N_LAYERS * 512) {
        int g = i >> 9, p = i & 511, blk = p >> 3, j = p & 7;
        float a = angles[i];
        _Float16* base = csh + g * 1024 + blk * 16;   // halves
        base[j]     = (_Float16)cosf(a);
        base[8 + j] = (_Float16)sinf(a);
    }
    if (i < N_DEPTH * N_INW) {
        int v = indices[i];
        addrs[i] = (v + (v >> 4)) << 2;
    }
}

// fp16 slab (per wave): row r -> half2 at byte (r + (r>>4))<<2.
#define ADDR(r) ((((r) + ((r) >> 4))) << 2)

#define LDH(A)    __builtin_bit_cast(h2, *(const unsigned*)(L + (A)))
#define STH(A, V) do { *(unsigned*)(L + (A)) =                                 \
                       __builtin_bit_cast(unsigned, (V)); } while (0)

#define PKU(x, y) __builtin_bit_cast(unsigned int,                             \
                      __builtin_amdgcn_cvt_pkrtz((x), (y)))

// broadcast lo/hi half of a packed uint (2 halves) into both lanes of an h2
#define BCL(U) ({ h2 _t = __builtin_bit_cast(h2, (unsigned)(U));               \
                  h2 _r; _r.x = _t.x; _r.y = _t.x; _r; })
#define BCH(U) ({ h2 _t = __builtin_bit_cast(h2, (unsigned)(U));               \
                  h2 _r; _r.x = _t.y; _r.y = _t.y; _r; })

// native packed-f16 2x2 rotation: v_pk_mul_f16 / v_pk_fma_f16
#define ROTPH(LO, HI, CC, SS) do { h2 _l = LO, _h = HI, _c = CC, _s = SS;      \
    LO = _c * _l + _s * _h; HI = _c * _h - _s * _l; } while (0)

// ---- per-set register state (A / B ping-pong, full-module prefetch) ----
#define DECL_SET(P)                                                            \
    uint4 P##c0, P##s0, P##c1, P##s1, P##c2, P##s2, P##c3, P##s3,              \
          P##c4, P##s4, P##c5, P##s5, P##c6, P##s6, P##c7, P##s7;              \
    int4  P##i0, P##i1, P##i2, P##i3;                                          \
    float4 P##bA, P##bB;

// synthesize one packed layer from angles (fallback path)
#define SYN1(P, K, ANB) do {                                                   \
    const float4* _p = (const float4*)((ANB) + (K)*512 + (blk << 3));          \
    float4 _u = _p[0], _v = _p[1];                                             \
    float _c0,_c1,_c2,_c3,_c4,_c5,_c6,_c7,_t0,_t1,_t2,_t3,_t4,_t5,_t6,_t7;     \
    __sincosf(_u.x,&_t0,&_c0); __sincosf(_u.y,&_t1,&_c1);                      \
    __sincosf(_u.z,&_t2,&_c2); __sincosf(_u.w,&_t3,&_c3);                      \
    __sincosf(_v.x,&_t4,&_c4); __sincosf(_v.y,&_t5,&_c5);                      \
    __sincosf(_v.z,&_t6,&_c6); __sincosf(_v.w,&_t7,&_c7);                      \
    P##c##K = make_uint4(PKU(_c0,_c1),PKU(_c2,_c3),PKU(_c4,_c5),PKU(_c6,_c7)); \
    P##s##K = make_uint4(PKU(_t0,_t1),PKU(_t2,_t3),PKU(_t4,_t5),PKU(_t6,_t7)); \
  } while (0)

#define LOADCS1(P, K, CSN, ANB) do { if (USE_TABLE) {                          \
    const char* _b = (CSN) + (blk << 5) + (K)*2048;                            \
    P##c##K = *(const uint4*)(_b); P##s##K = *(const uint4*)(_b + 16);         \
  } else { SYN1(P, K, ANB); } } while (0)

#define LOADCS8(P, CSN, ANB) do {                                              \
    LOADCS1(P,0,CSN,ANB); LOADCS1(P,1,CSN,ANB); LOADCS1(P,2,CSN,ANB);          \
    LOADCS1(P,3,CSN,ANB); LOADCS1(P,4,CSN,ANB); LOADCS1(P,5,CSN,ANB);          \
    LOADCS1(P,6,CSN,ANB); LOADCS1(P,7,CSN,ANB); } while (0)
#define LOADCS4(P, CSN, ANB) do {                                              \
    LOADCS1(P,0,CSN,ANB); LOADCS1(P,1,CSN,ANB); LOADCS1(P,2,CSN,ANB);          \
    LOADCS1(P,3,CSN,ANB); } while (0)

#define TR(v) (((v) + ((v) >> 4)) << 2)
#define LOAD_AB(P, ATN, INB, BIN) do { if (USE_TABLE) {                        \
    const int4* _ip = (const int4*)((ATN) + (blk << 4));                       \
    P##i0=_ip[0]; P##i1=_ip[1]; P##i2=_ip[2]; P##i3=_ip[3];                    \
  } else {                                                                     \
    const int4* _ip = (const int4*)((INB) + (blk << 4));                       \
    int4 _v0=_ip[0], _v1=_ip[1], _v2=_ip[2], _v3=_ip[3];                       \
    P##i0.x=TR(_v0.x); P##i0.y=TR(_v0.y); P##i0.z=TR(_v0.z); P##i0.w=TR(_v0.w);\
    P##i1.x=TR(_v1.x); P##i1.y=TR(_v1.y); P##i1.z=TR(_v1.z); P##i1.w=TR(_v1.w);\
    P##i2.x=TR(_v2.x); P##i2.y=TR(_v2.y); P##i2.z=TR(_v2.z); P##i2.w=TR(_v2.w);\
    P##i3.x=TR(_v3.x); P##i3.y=TR(_v3.y); P##i3.z=TR(_v3.z); P##i3.w=TR(_v3.w);\
  }                                                                            \
  const float4* _bp = (const float4*)((BIN) + (blk << 3));                     \
  P##bA = _bp[0]; P##bB = _bp[1]; } while (0)

// rotation layers consuming PACKED cs (value j: j0=lo(x),j1=hi(x),...,j7=hi(w))
#define HROTS1(C,S) do {                                                       \
    ROTPH(x0,x1,  BCL(C.x),BCL(S.x)); ROTPH(x2,x3,  BCH(C.x),BCH(S.x));        \
    ROTPH(x4,x5,  BCL(C.y),BCL(S.y)); ROTPH(x6,x7,  BCH(C.y),BCH(S.y));        \
    ROTPH(x8,x9,  BCL(C.z),BCL(S.z)); ROTPH(x10,x11,BCH(C.z),BCH(S.z));        \
    ROTPH(x12,x13,BCL(C.w),BCL(S.w)); ROTPH(x14,x15,BCH(C.w),BCH(S.w));        \
  } while (0)
#define HROTS2(C,S) do {                                                       \
    ROTPH(x0,x2,  BCL(C.x),BCL(S.x)); ROTPH(x1,x3,  BCH(C.x),BCH(S.x));        \
    ROTPH(x4,x6,  BCL(C.y),BCL(S.y)); ROTPH(x5,x7,  BCH(C.y),BCH(S.y));        \
    ROTPH(x8,x10, BCL(C.z),BCL(S.z)); ROTPH(x9,x11, BCH(C.z),BCH(S.z));        \
    ROTPH(x12,x14,BCL(C.w),BCL(S.w)); ROTPH(x13,x15,BCH(C.w),BCH(S.w));        \
  } while (0)
#define HROTS4(C,S) do {                                                       \
    ROTPH(x0,x4,  BCL(C.x),BCL(S.x)); ROTPH(x1,x5,  BCH(C.x),BCH(S.x));        \
    ROTPH(x2,x6,  BCL(C.y),BCL(S.y)); ROTPH(x3,x7,  BCH(C.y),BCH(S.y));        \
    ROTPH(x8,x12, BCL(C.z),BCL(S.z)); ROTPH(x9,x13, BCH(C.z),BCH(S.z));        \
    ROTPH(x10,x14,BCL(C.w),BCL(S.w)); ROTPH(x11,x15,BCH(C.w),BCH(S.w));        \
  } while (0)
#define HROTS8(C,S) do {                                                       \
    ROTPH(x0,x8,  BCL(C.x),BCL(S.x)); ROTPH(x1,x9,  BCH(C.x),BCH(S.x));        \
    ROTPH(x2,x10, BCL(C.y),BCL(S.y)); ROTPH(x3,x11, BCH(C.y),BCH(S.y));        \
    ROTPH(x4,x12, BCL(C.z),BCL(S.z)); ROTPH(x5,x13, BCH(C.z),BCH(S.z));        \
    ROTPH(x6,x14, BCL(C.w),BCL(S.w)); ROTPH(x7,x15, BCH(C.w),BCH(S.w));        \
  } while (0)

#define HROT(P, K, M) M(P##c##K, P##s##K)

// activation in fp32 (values are h2 in registers; bias fp32 scalar per row)
#define ACTH(X, BF) do {                                                       \
    float _lo = (float)(X).x + (BF), _hi = (float)(X).y + (BF);                \
    _lo = 0.5f * (_lo + __builtin_amdgcn_sqrtf(_lo * _lo + 1.0f));             \
    _hi = 0.5f * (_hi + __builtin_amdgcn_sqrtf(_hi * _hi + 1.0f));             \
    X = __builtin_bit_cast(h2, PKU(_lo, _hi)); } while (0)

#define FENCE() __builtin_amdgcn_sched_barrier(0)

// process module M with set P; prefetch next module into set N (FULL=all 8
// layers, else IN 4 only). Barrier-free (each wave owns its private slab);
// fenced load blocks keep full-module prefetch distance (r10: +34% win).
#define PROC_MOD(P, N, CSN, ANN, ATN, INB, BIN, M, FULL) do {                  \
  const int a0=P##i0.x, a1=P##i0.y, a2=P##i0.z, a3=P##i0.w,                    \
            a4=P##i1.x, a5=P##i1.y, a6=P##i1.z, a7=P##i1.w,                    \
            a8=P##i2.x, a9=P##i2.y, a10=P##i2.z, a11=P##i2.w,                  \
            a12=P##i3.x, a13=P##i3.y, a14=P##i3.z, a15=P##i3.w;                \
  h2 x0=LDH(a0), x1=LDH(a1), x2=LDH(a2), x3=LDH(a3),                           \
     x4=LDH(a4), x5=LDH(a5), x6=LDH(a6), x7=LDH(a7),                           \
     x8=LDH(a8), x9=LDH(a9), x10=LDH(a10), x11=LDH(a11),                       \
     x12=LDH(a12), x13=LDH(a13), x14=LDH(a14), x15=LDH(a15);                   \
  if (FULL) { LOADCS8(N, CSN, ANN); } else { LOADCS4(N, CSN, ANN); }           \
  FENCE();                                                                     \
  HROT(P,0,HROTS1); HROT(P,1,HROTS2); HROT(P,2,HROTS4); HROT(P,3,HROTS8);      \
  ACTH(x0,P##bA.x); ACTH(x1,P##bA.y); ACTH(x2,P##bA.z); ACTH(x3,P##bA.w);      \
  ACTH(x4,P##bB.x); ACTH(x5,P##bB.y); ACTH(x6,P##bB.z); ACTH(x7,P##bB.w);      \
  const int _ab = ADDR(N_INW + (M)*N_GROW + (blk << 3));                       \
  STH(_ab+ 0,x0); STH(_ab+ 4,x1); STH(_ab+ 8,x2); STH(_ab+12,x3);              \
  STH(_ab+16,x4); STH(_ab+20,x5); STH(_ab+24,x6); STH(_ab+28,x7);              \
  LOAD_AB(N, ATN, INB, BIN);                                                   \
  FENCE();                                                                     \
  HROT(P,4,HROTS1); HROT(P,5,HROTS2); HROT(P,6,HROTS4); HROT(P,7,HROTS8);      \
  STH(a0,x0);  STH(a1,x1);  STH(a2,x2);  STH(a3,x3);                           \
  STH(a4,x4);  STH(a5,x5);  STH(a6,x6);  STH(a7,x7);                           \
  STH(a8,x8);  STH(a9,x9);  STH(a10,x10); STH(a11,x11);                        \
  STH(a12,x12); STH(a13,x13); STH(a14,x14); STH(a15,x15);                      \
} while (0)

template <bool USE_TABLE>
__global__ __launch_bounds__(N_THREADS, 2)   // <=256 VGPR
void butterfly_fused_kernel(const float* __restrict__ input,
                            const float* __restrict__ scales,
                            const float* __restrict__ biases,
                            const int*   __restrict__ indices,
                            const char*  __restrict__ cs_tab,
                            const int*   __restrict__ addr_tab,
                            const float* __restrict__ angles,
                            float* __restrict__ out) {
    extern __shared__ float ldsbuf[];
    const int t   = threadIdx.x;
    const int blk = t & 63;          // butterfly block = lane
    const int cp  = t >> 6;          // wave id; waves fully independent
    char* L = (char*)ldsbuf + cp * SLAB_B;   // private per-wave slab
    const int b   = blockIdx.x;
    // XCD swizzle: blockIdx%8 == x owns columns [x*512,(x+1)*512)
    const int cg  = ((((b & 7) * 128) + (b >> 3)) << 2) + (cp << 1);

    DECL_SET(A) DECL_SET(B)

    // prologue: module 0 params into A
    LOADCS8(A, cs_tab, angles);
    LOAD_AB(A, addr_tab, indices, biases);

    // init: rows 0..1023 = scales[r] * input[r][cg..cg+1] (fp16 pack)
#pragma unroll
    for (int k = 0; k < 16; ++k) {
        const int r = (k << 6) + blk;
        F2 v = *(const F2*)(input + (size_t)r * N_BATCH + cg);
        STH(ADDR(r), __builtin_bit_cast(h2, PKU(scales[r] * v.x, scales[r] * v.y)));
    }

    // next-module bases (module 1)
    const char*  csn = cs_tab + 16384;
    const float* ann = angles + 4096;
    const int*   atn = addr_tab + N_INW;
    const int*   inb = indices + N_INW;
    const float* bin = biases + N_GROW;

#pragma unroll 1
    for (int tt = 0; tt < 3; ++tt) {
        const int m = 2 * tt;
        PROC_MOD(A, B, csn, ann, atn, inb, bin, m, 1);
        csn += 16384; ann += 4096; atn += N_INW; inb += N_INW; bin += N_GROW;
        PROC_MOD(B, A, csn, ann, atn, inb, bin, m + 1, 1);
        csn += 16384; ann += 4096; atn += N_INW; inb += N_INW; bin += N_GROW;
    }
    // module 6 (A), prefetching module 7's IN layers into B
    PROC_MOD(A, B, csn, ann, atn, inb, bin, 6, 0);

    // epilogue: module 7 (B) — OUT rotations + scatter are dead code;
    // output = module-7 activations (convert fp16 -> fp32).
    {
        h2 x0=LDH(Bi0.x), x1=LDH(Bi0.y), x2=LDH(Bi0.z), x3=LDH(Bi0.w),
           x4=LDH(Bi1.x), x5=LDH(Bi1.y), x6=LDH(Bi1.z), x7=LDH(Bi1.w),
           x8=LDH(Bi2.x), x9=LDH(Bi2.y), x10=LDH(Bi2.z), x11=LDH(Bi2.w),
           x12=LDH(Bi3.x), x13=LDH(Bi3.y), x14=LDH(Bi3.z), x15=LDH(Bi3.w);
        FENCE();
        HROT(B,0,HROTS1); HROT(B,1,HROTS2); HROT(B,2,HROTS4); HROT(B,3,HROTS8);
        ACTH(x0,BbA.x); ACTH(x1,BbA.y); ACTH(x2,BbA.z); ACTH(x3,BbA.w);
        ACTH(x4,BbB.x); ACTH(x5,BbB.y); ACTH(x6,BbB.z); ACTH(x7,BbB.w);
#define OUTW(J, X) do { F2 _o; _o.x = (float)(X).x; _o.y = (float)(X).y;       \
        *(F2*)(out + (size_t)((blk<<3)+(J))*N_BATCH + cg) = _o; } while (0)
        OUTW(0,x0); OUTW(1,x1); OUTW(2,x2); OUTW(3,x3);
        OUTW(4,x4); OUTW(5,x5); OUTW(6,x6); OUTW(7,x7);
#undef OUTW
    }
}

// ---------------- host ----------------
extern "C" void kernel_launch(void* const* d_in, const int* in_sizes, int n_in,
                              void* d_out, int out_size, void* d_ws, size_t ws_size,
                              hipStream_t stream) {
    const float* input   = (const float*)d_in[0];
    const float* scales  = (const float*)d_in[1];
    const float* angles  = (const float*)d_in[2];
    const float* biases  = (const float*)d_in[3];
    const int*   indices = (const int*)d_in[4];
    float* out = (float*)d_out;

    const size_t cs_bytes  = (size_t)N_LAYERS * 2048;                    // 128 KB fp16
    const size_t adr_bytes = (size_t)N_DEPTH * N_INW * sizeof(int);      // 32 KB
    const size_t lds_bytes = (size_t)2 * SLAB_B;                         // 39168 B
    const int grid = N_BATCH / 4;                                        // 1024 WGs

    if (ws_size >= cs_bytes + adr_bytes) {
        _Float16* csh = (_Float16*)d_ws;
        int* addrs = (int*)((char*)d_ws + cs_bytes);
        precompute_kernel<<<(N_LAYERS * 512 + 255) / 256, 256, 0, stream>>>(
            angles, indices, csh, addrs);
        butterfly_fused_kernel<true><<<grid, N_THREADS, lds_bytes, stream>>>(
            input, scales, biases, indices, (const char*)csh, addrs, angles, out);
    } else {
        butterfly_fused_kernel<false><<<grid, N_THREADS, lds_bytes, stream>>>(
            input, scales, biases, indices, nullptr, nullptr, angles, out);
    }
}